// Round 4
// baseline (148.365 us; speedup 1.0000x reference)
//
#include <hip/hip_runtime.h>
#include <math.h>

#define NB 4
#define NL 2048
#define ND 768
#define NH 12
#define NK 9
#define NIPG 64
#define NPAD 4
#define MT 112          // output rows per gemm_conv block (stages MT+16 v-rows)

typedef __attribute__((ext_vector_type(8))) short s16x8;
typedef __attribute__((ext_vector_type(4))) float f32x4;

__device__ __forceinline__ unsigned short f2bf(float f) {
  unsigned int u = __float_as_uint(f);
  unsigned int r = (u + 0x7FFFu + ((u >> 16) & 1u)) >> 16;
  return (unsigned short)r;
}
__device__ __forceinline__ float bf2f(unsigned short s) {
  return __uint_as_float(((unsigned int)s) << 16);
}
__device__ __forceinline__ void gload16(const void* g, void* l) {
  __builtin_amdgcn_global_load_lds((const __attribute__((address_space(1))) void*)g,
                                   (__attribute__((address_space(3))) void*)l,
                                   16, 0, 0);
}

// ---------------------------------------------------------------------------
// Kernel 0: weight prep — pt_w -> ptb (bf16), pw_w -> pwb, ak_w -> akp
// (k-padded to 16 with zeros).  576 blocks x 256.
// ---------------------------------------------------------------------------
__global__ __launch_bounds__(256) void prep(const float* __restrict__ pt_w,
                                            const float* __restrict__ pw_w,
                                            const float* __restrict__ ak_w,
                                            unsigned short* __restrict__ ptb,
                                            unsigned short* __restrict__ pwb,
                                            unsigned short* __restrict__ akp) {
  const int t = blockIdx.x * 256 + threadIdx.x;
  if (t < ND * ND / 4) {
    float4 f = ((const float4*)pt_w)[t];
    ushort4 o; o.x = f2bf(f.x); o.y = f2bf(f.y); o.z = f2bf(f.z); o.w = f2bf(f.w);
    ((ushort4*)ptb)[t] = o;
  }
  if (t < NH * NIPG * NIPG / 4) {
    float4 f = ((const float4*)pw_w)[t];
    ushort4 o; o.x = f2bf(f.x); o.y = f2bf(f.y); o.z = f2bf(f.z); o.w = f2bf(f.w);
    ((ushort4*)pwb)[t] = o;
  }
  if (t < NH * 16 * NIPG) {
    const int h = t >> 10;
    const int r = t & 1023;
    const int k = r >> 6;
    const int i = r & 63;
    akp[t] = (k < NK) ? f2bf(ak_w[((size_t)h * NK + k) * NIPG + i]) : (unsigned short)0;
  }
}

// ---------------------------------------------------------------------------
// Kernel 1: dynamic conv weights (MFMA) + emits qb = bf16(query).
// Identical structure to round-3 attn_w (verified) + one ushort4 store.
// ---------------------------------------------------------------------------
__global__ __launch_bounds__(256) void attn_w(const float* __restrict__ q,
                                              const float* __restrict__ dw_w,
                                              const unsigned short* __restrict__ pwb,
                                              const float* __restrict__ pw_b,
                                              const unsigned short* __restrict__ akp,
                                              const float* __restrict__ ak_b,
                                              float* __restrict__ wout,
                                              unsigned short* __restrict__ qb) {
  __shared__ float qs[72][68];
  __shared__ unsigned char ab[8192];    // [64][64] bf16, byte ^= (row&7)<<4
  const int l0 = blockIdx.x * 64;
  const int h  = blockIdx.y;
  const int b  = blockIdx.z;
  const int d0 = h * NIPG;
  const int t  = threadIdx.x;
  const int lane = t & 63;
  const int wv = t >> 6;

  // stage q rows l0-4 .. l0+67; rows [4,68) also emit bf16 to qb
  {
    const int sl = t >> 4;
    const int sc = (t & 15) * 4;
    for (int r = sl; r < 72; r += 16) {
      const int l = l0 - NPAD + r;
      float4 val = make_float4(0.f, 0.f, 0.f, 0.f);
      if (l >= 0 && l < NL) val = *(const float4*)&q[((size_t)(b * NL + l)) * ND + d0 + sc];
      *(float4*)&qs[r][sc] = val;
      if (r >= NPAD && r < NPAD + 64) {
        ushort4 ub;
        ub.x = f2bf(val.x); ub.y = f2bf(val.y); ub.z = f2bf(val.z); ub.w = f2bf(val.w);
        *(ushort4*)&qb[((size_t)(b * NL + l)) * ND + d0 + sc] = ub;
      }
    }
  }
  float dwk[NK];
#pragma unroll
  for (int k = 0; k < NK; ++k) dwk[k] = dw_w[(size_t)(d0 + lane) * NK + k];
  __syncthreads();

  const int lset = wv * 16;
#pragma unroll
  for (int l2 = 0; l2 < 16; ++l2) {
    const int l = lset + l2;
    float s = 0.f;
#pragma unroll
    for (int k = 0; k < NK; ++k) s = fmaf(qs[l + k][lane], dwk[k], s);
    const int byte = ((l * 64 + lane) * 2) ^ ((l & 7) << 4);
    *(unsigned short*)&ab[byte] = f2bf(s);
  }
  __syncthreads();

  const int fr = lane & 15;
  const int fq = lane >> 4;

  s16x8 av0, av1;
  {
    const int row = lset + fr;
    const int b0 = ((row * 64 + fq * 8) * 2)      ^ ((row & 7) << 4);
    const int b1 = ((row * 64 + 32 + fq * 8) * 2) ^ ((row & 7) << 4);
    av0 = *(const s16x8*)&ab[b0];
    av1 = *(const s16x8*)&ab[b1];
  }
  const unsigned short* pwh = pwb + (size_t)h * NIPG * NIPG;
  f32x4 accp[4];
#pragma unroll
  for (int n = 0; n < 4; ++n) {
    accp[n] = (f32x4){0.f, 0.f, 0.f, 0.f};
    const int o = n * 16 + fr;
    s16x8 bv0 = *(const s16x8*)&pwh[o * 64 + fq * 8];
    s16x8 bv1 = *(const s16x8*)&pwh[o * 64 + 32 + fq * 8];
    accp[n] = __builtin_amdgcn_mfma_f32_16x16x32_bf16(av0, bv0, accp[n], 0, 0, 0);
    accp[n] = __builtin_amdgcn_mfma_f32_16x16x32_bf16(av1, bv1, accp[n], 0, 0, 0);
  }
  __syncthreads();

#pragma unroll
  for (int n = 0; n < 4; ++n) {
    const int o = n * 16 + fr;
    const float pb = pw_b[d0 + o];
#pragma unroll
    for (int j = 0; j < 4; ++j) {
      const int row = lset + fq * 4 + j;
      const float ca = (accp[n][j] + pb) * qs[row + NPAD][o];
      const int byte = ((row * 64 + o) * 2) ^ ((row & 7) << 4);
      *(unsigned short*)&ab[byte] = f2bf(ca);
    }
  }
  __syncthreads();

  f32x4 acck = (f32x4){0.f, 0.f, 0.f, 0.f};
  {
    const int row = lset + fr;
    const int b0 = ((row * 64 + fq * 8) * 2)      ^ ((row & 7) << 4);
    const int b1 = ((row * 64 + 32 + fq * 8) * 2) ^ ((row & 7) << 4);
    s16x8 a0 = *(const s16x8*)&ab[b0];
    s16x8 a1 = *(const s16x8*)&ab[b1];
    const unsigned short* akh = akp + (size_t)h * 16 * NIPG;
    s16x8 b0v = *(const s16x8*)&akh[fr * 64 + fq * 8];
    s16x8 b1v = *(const s16x8*)&akh[fr * 64 + 32 + fq * 8];
    acck = __builtin_amdgcn_mfma_f32_16x16x32_bf16(a0, b0v, acck, 0, 0, 0);
    acck = __builtin_amdgcn_mfma_f32_16x16x32_bf16(a1, b1v, acck, 0, 0, 0);
  }

  const bool kvalid = fr < NK;
  const float akbv = kvalid ? ak_b[h * NK + fr] : 0.f;
#pragma unroll
  for (int j = 0; j < 4; ++j) {
    float val = acck[j] + akbv;
    float mv = kvalid ? val : -3.4e38f;
#pragma unroll
    for (int mm = 1; mm < 16; mm <<= 1) mv = fmaxf(mv, __shfl_xor(mv, mm));
    const float e = kvalid ? __expf(val - mv) : 0.f;
    float ssum = e;
#pragma unroll
    for (int mm = 1; mm < 16; mm <<= 1) ssum += __shfl_xor(ssum, mm);
    if (kvalid) {
      const int row = l0 + lset + fq * 4 + j;
      wout[(((size_t)(b * NL + row)) * NH + h) * NK + fr] = e / ssum;
    }
  }
}

// ---------------------------------------------------------------------------
// Kernel 2: fused v-GEMM + 9-tap span conv.
// Block: output rows [mo, mo+112) x cols [n0, n0+128).  Stages 128 v-rows
// (mo-8 .. mo+119) via 128x128 MFMA tile (2-phase double-buffered staging),
// dumps v-tile to LDS bf16, applies conv with w, writes out f32.
// ---------------------------------------------------------------------------
__global__ __launch_bounds__(256) void gemm_conv(const unsigned short* __restrict__ qb,
                                                 const unsigned short* __restrict__ ptb,
                                                 const float* __restrict__ bias,
                                                 const float* __restrict__ w,
                                                 float* __restrict__ out) {
  __shared__ unsigned char lds[33792];   // 2x16KB staging; vtile [128][132] bf16
  const int t = threadIdx.x;
  const long mo = (long)blockIdx.x * MT;
  const int n0 = blockIdx.y * 128;
  const int lane = t & 63;
  const int wv = t >> 6;
  const int wr = wv >> 1, wc = wv & 1;
  const int fr = lane & 15;
  const int fq = lane >> 4;

  // staging addresses (A rows mo-8+sr may be <0 or >=8192: lands in adjacent
  // d_ws arrays — harmless, masked at use)
  const int soff = t * 16;
  const int sr = soff >> 6;
  const int scb = soff & 63;
  const unsigned char* gA0 = (const unsigned char*)qb + (mo - 8 + sr) * (long)(ND * 2) + scb;
  const unsigned char* gA1 = gA0 + (long)64 * (ND * 2);
  const unsigned char* gB0 = (const unsigned char*)ptb + (size_t)(n0 + sr) * (ND * 2) + scb;
  const unsigned char* gB1 = gB0 + (size_t)64 * (ND * 2);

  int aoff[4], boff[4];
#pragma unroll
  for (int m = 0; m < 4; ++m)
    aoff[m] = ((wr * 64 + m * 16 + fr) * 32 + fq * 8) * 2;
#pragma unroll
  for (int n = 0; n < 4; ++n)
    boff[n] = 8192 + ((wc * 64 + n * 16 + fr) * 32 + fq * 8) * 2;

#define STAGE(kt, buf)                                             \
  do {                                                             \
    const long kb_ = (long)(kt) * 64;                              \
    unsigned char* base_ = &lds[(buf) * 16384];                    \
    gload16(gA0 + kb_, base_ + soff);                              \
    gload16(gA1 + kb_, base_ + 4096 + soff);                       \
    gload16(gB0 + kb_, base_ + 8192 + soff);                       \
    gload16(gB1 + kb_, base_ + 12288 + soff);                      \
  } while (0)

  f32x4 acc[4][4] = {};
  STAGE(0, 0);
  __syncthreads();                        // drain tile 0 only
  for (int kt = 0; kt < ND / 32; ++kt) {
    const int cur = kt & 1;
    if (kt + 1 < ND / 32) STAGE(kt + 1, cur ^ 1);   // prefetch overlaps compute
    const unsigned char* bb = &lds[cur * 16384];
    s16x8 av[4], bv[4];
#pragma unroll
    for (int m = 0; m < 4; ++m) av[m] = *(const s16x8*)&bb[aoff[m]];
#pragma unroll
    for (int n = 0; n < 4; ++n) bv[n] = *(const s16x8*)&bb[boff[n]];
#pragma unroll
    for (int m = 0; m < 4; ++m)
#pragma unroll
      for (int n = 0; n < 4; ++n)
        acc[m][n] = __builtin_amdgcn_mfma_f32_16x16x32_bf16(av[m], bv[n], acc[m][n], 0, 0, 0);
    __syncthreads();                      // drain prefetch + reads-before-overwrite
  }
#undef STAGE

  // dump v-tile (+bias) to LDS bf16, row stride 132
  unsigned short* vt = (unsigned short*)lds;
#pragma unroll
  for (int m = 0; m < 4; ++m) {
#pragma unroll
    for (int n = 0; n < 4; ++n) {
      const int rb = wr * 64 + m * 16 + fq * 4;
      const int cc = wc * 64 + n * 16 + fr;
      const float bbv = bias[n0 + cc];
#pragma unroll
      for (int j = 0; j < 4; ++j)
        vt[(rb + j) * 132 + cc] = f2bf(acc[m][n][j] + bbv);
    }
  }
  __syncthreads();

  // conv: thread owns col-quad cq, 14 consecutive rows. Rolling 9-row window.
  const int cq = (t & 31) * 4;
  const int r0 = 8 + (t >> 5) * 14;
  const int h = (n0 + cq) >> 6;
  float4 win[NK];
#pragma unroll
  for (int k = 0; k < NK; ++k) {
    ushort4 u = *(const ushort4*)&vt[(r0 - 4 + k) * 132 + cq];
    win[k] = make_float4(bf2f(u.x), bf2f(u.y), bf2f(u.z), bf2f(u.w));
  }
#pragma unroll
  for (int i = 0; i < 14; ++i) {
    const int r = r0 + i;
    const long g = mo + r - 8;            // global output row (b*NL + l)
    if (g < (long)NB * NL) {
      const int l = (int)(g & (NL - 1));
      const float* wp = &w[((size_t)g * NH + h) * NK];
      float4 a = make_float4(0.f, 0.f, 0.f, 0.f);
#pragma unroll
      for (int k = 0; k < NK; ++k) {
        const int lk = l + k - NPAD;
        if (lk >= 0 && lk < NL) {
          const float wk = wp[k];
          a.x = fmaf(wk, win[k].x, a.x);
          a.y = fmaf(wk, win[k].y, a.y);
          a.z = fmaf(wk, win[k].z, a.z);
          a.w = fmaf(wk, win[k].w, a.w);
        }
      }
      *(float4*)&out[(size_t)g * ND + n0 + cq] = a;
    }
    if (i < 13) {
#pragma unroll
      for (int k = 0; k < NK - 1; ++k) win[k] = win[k + 1];
      ushort4 u = *(const ushort4*)&vt[(r + 5) * 132 + cq];
      win[NK - 1] = make_float4(bf2f(u.x), bf2f(u.y), bf2f(u.z), bf2f(u.w));
    }
  }
}

// ---------------------------------------------------------------------------
extern "C" void kernel_launch(void* const* d_in, const int* in_sizes, int n_in,
                              void* d_out, int out_size, void* d_ws, size_t ws_size,
                              hipStream_t stream) {
  const float* query = (const float*)d_in[0];
  const float* dw_w  = (const float*)d_in[1];
  const float* pw_w  = (const float*)d_in[2];
  const float* pw_b  = (const float*)d_in[3];
  const float* ak_w  = (const float*)d_in[4];
  const float* ak_b  = (const float*)d_in[5];
  const float* pt_w  = (const float*)d_in[6];
  const float* pt_b  = (const float*)d_in[7];
  float* out = (float*)d_out;

  // workspace: w first (gives qb a safe negative-offset apron), then qb, ptb…
  float* w = (float*)d_ws;                                        // 3.54MB
  unsigned short* qb  = (unsigned short*)(w + (size_t)NB * NL * NH * NK); // 12.6MB
  unsigned short* ptb = qb + (size_t)NB * NL * ND;                // 1.18MB
  unsigned short* pwb = ptb + (size_t)ND * ND;                    // 98KB
  unsigned short* akp = pwb + (size_t)NH * NIPG * NIPG;           // 24.6KB

  prep<<<ND * ND / 4 / 256, 256, 0, stream>>>(pt_w, pw_w, ak_w, ptb, pwb, akp);

  dim3 g2(NL / 64, NH, NB);
  attn_w<<<g2, 256, 0, stream>>>(query, dw_w, pwb, pw_b, akp, ak_b, w, qb);

  dim3 g3((NB * NL + MT - 1) / MT, ND / 128, 1);
  gemm_conv<<<g3, 256, 0, stream>>>(qb, ptb, pt_b, w, out);
}

// Round 5
// 141.118 us; speedup vs baseline: 1.0514x; 1.0514x over previous
//
#include <hip/hip_runtime.h>
#include <math.h>

#define NB 4
#define NL 2048
#define ND 768
#define NH 12
#define NK 9
#define NIPG 64
#define NPAD 4
#define MT 112          // output rows per gemm_conv block (stages 128 v-rows)

typedef __attribute__((ext_vector_type(8))) short s16x8;
typedef __attribute__((ext_vector_type(4))) float f32x4;

__device__ __forceinline__ unsigned short f2bf(float f) {
  unsigned int u = __float_as_uint(f);
  unsigned int r = (u + 0x7FFFu + ((u >> 16) & 1u)) >> 16;
  return (unsigned short)r;
}
__device__ __forceinline__ float bf2f(unsigned short s) {
  return __uint_as_float(((unsigned int)s) << 16);
}
__device__ __forceinline__ void gload16(const void* g, void* l) {
  __builtin_amdgcn_global_load_lds((const __attribute__((address_space(1))) void*)g,
                                   (__attribute__((address_space(3))) void*)l,
                                   16, 0, 0);
}

// ---------------------------------------------------------------------------
// Kernel 0: weight prep — pt_w -> ptb (bf16), pw_w -> pwb, ak_w -> akp
// (k-padded to 16 with zeros).
// ---------------------------------------------------------------------------
__global__ __launch_bounds__(256) void prep(const float* __restrict__ pt_w,
                                            const float* __restrict__ pw_w,
                                            const float* __restrict__ ak_w,
                                            unsigned short* __restrict__ ptb,
                                            unsigned short* __restrict__ pwb,
                                            unsigned short* __restrict__ akp) {
  const int t = blockIdx.x * 256 + threadIdx.x;
  if (t < ND * ND / 4) {
    float4 f = ((const float4*)pt_w)[t];
    ushort4 o; o.x = f2bf(f.x); o.y = f2bf(f.y); o.z = f2bf(f.z); o.w = f2bf(f.w);
    ((ushort4*)ptb)[t] = o;
  }
  if (t < NH * NIPG * NIPG / 4) {
    float4 f = ((const float4*)pw_w)[t];
    ushort4 o; o.x = f2bf(f.x); o.y = f2bf(f.y); o.z = f2bf(f.z); o.w = f2bf(f.w);
    ((ushort4*)pwb)[t] = o;
  }
  if (t < NH * 16 * NIPG) {
    const int h = t >> 10;
    const int r = t & 1023;
    const int k = r >> 6;
    const int i = r & 63;
    akp[t] = (k < NK) ? f2bf(ak_w[((size_t)h * NK + k) * NIPG + i]) : (unsigned short)0;
  }
}

// ---------------------------------------------------------------------------
// Kernel 1: dynamic conv weights (MFMA) + emits qb = bf16(query).
// qs now bf16 (LDS 27.6 -> 17.8 KB); depthwise conv uses a rolling 9-reg
// window (24 LDS reads/thread instead of 144).
// ---------------------------------------------------------------------------
__global__ __launch_bounds__(256) void attn_w(const float* __restrict__ q,
                                              const float* __restrict__ dw_w,
                                              const unsigned short* __restrict__ pwb,
                                              const float* __restrict__ pw_b,
                                              const unsigned short* __restrict__ akp,
                                              const float* __restrict__ ak_b,
                                              float* __restrict__ wout,
                                              unsigned short* __restrict__ qb) {
  __shared__ unsigned short qs[72][68];   // bf16, stride 68 rotates banks
  __shared__ unsigned char ab[8192];      // [64][64] bf16, byte ^= (row&7)<<4
  const int l0 = blockIdx.x * 64;
  const int h  = blockIdx.y;
  const int b  = blockIdx.z;
  const int d0 = h * NIPG;
  const int t  = threadIdx.x;
  const int lane = t & 63;
  const int wv = t >> 6;

  // stage q rows l0-4 .. l0+67 as bf16; rows [4,68) also emit to qb
  {
    const int sl = t >> 4;
    const int sc = (t & 15) * 4;
    for (int r = sl; r < 72; r += 16) {
      const int l = l0 - NPAD + r;
      ushort4 ub = make_ushort4(0, 0, 0, 0);
      if (l >= 0 && l < NL) {
        float4 val = *(const float4*)&q[((size_t)(b * NL + l)) * ND + d0 + sc];
        ub.x = f2bf(val.x); ub.y = f2bf(val.y); ub.z = f2bf(val.z); ub.w = f2bf(val.w);
        if (r >= NPAD && r < NPAD + 64)
          *(ushort4*)&qb[((size_t)(b * NL + l)) * ND + d0 + sc] = ub;
      }
      *(ushort4*)&qs[r][sc] = ub;
    }
  }
  float dwk[NK];
#pragma unroll
  for (int k = 0; k < NK; ++k) dwk[k] = dw_w[(size_t)(d0 + lane) * NK + k];
  __syncthreads();

  // depthwise conv, rolling window; write bf16 swizzled
  const int lset = wv * 16;
  {
    float win9[NK];
#pragma unroll
    for (int k = 0; k < NK; ++k) win9[k] = bf2f(qs[lset + k][lane]);
#pragma unroll
    for (int l2 = 0; l2 < 16; ++l2) {
      const int l = lset + l2;
      float s = 0.f;
#pragma unroll
      for (int k = 0; k < NK; ++k) s = fmaf(win9[k], dwk[k], s);
      const int byte = ((l * 64 + lane) * 2) ^ ((l & 7) << 4);
      *(unsigned short*)&ab[byte] = f2bf(s);
      if (l2 < 15) {
#pragma unroll
        for (int k = 0; k < NK - 1; ++k) win9[k] = win9[k + 1];
        win9[NK - 1] = bf2f(qs[lset + l2 + NK][lane]);
      }
    }
  }
  __syncthreads();

  const int fr = lane & 15;
  const int fq = lane >> 4;

  // MFMA #1: pw[l][o] = dw[l][:] . pw_w[h][o][:]
  s16x8 av0, av1;
  {
    const int row = lset + fr;
    const int b0 = ((row * 64 + fq * 8) * 2)      ^ ((row & 7) << 4);
    const int b1 = ((row * 64 + 32 + fq * 8) * 2) ^ ((row & 7) << 4);
    av0 = *(const s16x8*)&ab[b0];
    av1 = *(const s16x8*)&ab[b1];
  }
  const unsigned short* pwh = pwb + (size_t)h * NIPG * NIPG;
  f32x4 accp[4];
#pragma unroll
  for (int n = 0; n < 4; ++n) {
    accp[n] = (f32x4){0.f, 0.f, 0.f, 0.f};
    const int o = n * 16 + fr;
    s16x8 bv0 = *(const s16x8*)&pwh[o * 64 + fq * 8];
    s16x8 bv1 = *(const s16x8*)&pwh[o * 64 + 32 + fq * 8];
    accp[n] = __builtin_amdgcn_mfma_f32_16x16x32_bf16(av0, bv0, accp[n], 0, 0, 0);
    accp[n] = __builtin_amdgcn_mfma_f32_16x16x32_bf16(av1, bv1, accp[n], 0, 0, 0);
  }
  __syncthreads();   // av reads complete before ab overwrite

  // ca = (pw + pw_b) * q -> ab (bf16 swizzled). C/D: row=(fq*4+j), col=o.
#pragma unroll
  for (int n = 0; n < 4; ++n) {
    const int o = n * 16 + fr;
    const float pb = pw_b[d0 + o];
#pragma unroll
    for (int j = 0; j < 4; ++j) {
      const int row = lset + fq * 4 + j;
      const float ca = (accp[n][j] + pb) * bf2f(qs[row + NPAD][o]);
      const int byte = ((row * 64 + o) * 2) ^ ((row & 7) << 4);
      *(unsigned short*)&ab[byte] = f2bf(ca);
    }
  }
  __syncthreads();

  // MFMA #2: kern[l][k] = ca[l][:] . ak_w[h][k][:]  (k padded to 16)
  f32x4 acck = (f32x4){0.f, 0.f, 0.f, 0.f};
  {
    const int row = lset + fr;
    const int b0 = ((row * 64 + fq * 8) * 2)      ^ ((row & 7) << 4);
    const int b1 = ((row * 64 + 32 + fq * 8) * 2) ^ ((row & 7) << 4);
    s16x8 a0 = *(const s16x8*)&ab[b0];
    s16x8 a1 = *(const s16x8*)&ab[b1];
    const unsigned short* akh = akp + (size_t)h * 16 * NIPG;
    s16x8 b0v = *(const s16x8*)&akh[fr * 64 + fq * 8];
    s16x8 b1v = *(const s16x8*)&akh[fr * 64 + 32 + fq * 8];
    acck = __builtin_amdgcn_mfma_f32_16x16x32_bf16(a0, b0v, acck, 0, 0, 0);
    acck = __builtin_amdgcn_mfma_f32_16x16x32_bf16(a1, b1v, acck, 0, 0, 0);
  }

  const bool kvalid = fr < NK;
  const float akbv = kvalid ? ak_b[h * NK + fr] : 0.f;
#pragma unroll
  for (int j = 0; j < 4; ++j) {
    float val = acck[j] + akbv;
    float mv = kvalid ? val : -3.4e38f;
#pragma unroll
    for (int mm = 1; mm < 16; mm <<= 1) mv = fmaxf(mv, __shfl_xor(mv, mm));
    const float e = kvalid ? __expf(val - mv) : 0.f;
    float ssum = e;
#pragma unroll
    for (int mm = 1; mm < 16; mm <<= 1) ssum += __shfl_xor(ssum, mm);
    if (kvalid) {
      const int row = l0 + lset + fq * 4 + j;
      wout[(((size_t)(b * NL + row)) * NH + h) * NK + fr] = e / ssum;
    }
  }
}

// ---------------------------------------------------------------------------
// Kernel 2: fused v-GEMM + 9-tap span conv.  128(M) x 64(N) tile -> 74x12 =
// 888 blocks (3.5/CU) for cross-block latency hiding.  Each block serves one
// head (h = n0/64).  Stages rows mo-8 .. mo+119, outputs rows [mo, mo+112).
// ---------------------------------------------------------------------------
__global__ __launch_bounds__(256) void gemm_conv(const unsigned short* __restrict__ qb,
                                                 const unsigned short* __restrict__ ptb,
                                                 const float* __restrict__ bias,
                                                 const float* __restrict__ w,
                                                 float* __restrict__ out) {
  __shared__ unsigned char lds[24576];   // 2 x (A 8KB | B 4KB); vtile overlay
  const int t = threadIdx.x;
  const long mo = (long)blockIdx.x * MT;
  const int n0 = blockIdx.y * 64;
  const int lane = t & 63;
  const int wv = t >> 6;
  const int fr = lane & 15;
  const int fq = lane >> 4;

  // staging (A rows mo-8+sr may be <0 or >=8192: lands inside d_ws — masked at use)
  const int soff = t * 16;
  const int sr = soff >> 6;
  const int scb = soff & 63;
  const unsigned char* gA0 = (const unsigned char*)qb + (mo - 8 + sr) * (long)(ND * 2) + scb;
  const unsigned char* gA1 = gA0 + (long)64 * (ND * 2);
  const unsigned char* gB  = (const unsigned char*)ptb + (size_t)(n0 + sr) * (ND * 2) + scb;

  int aoff[2], boff[4];
#pragma unroll
  for (int m = 0; m < 2; ++m)
    aoff[m] = ((wv * 32 + m * 16 + fr) * 32 + fq * 8) * 2;
#pragma unroll
  for (int n = 0; n < 4; ++n)
    boff[n] = 8192 + ((n * 16 + fr) * 32 + fq * 8) * 2;

#define STAGE(kt, buf)                                             \
  do {                                                             \
    const long kb_ = (long)(kt) * 64;                              \
    unsigned char* base_ = &lds[(buf) * 12288];                    \
    gload16(gA0 + kb_, base_ + soff);                              \
    gload16(gA1 + kb_, base_ + 4096 + soff);                       \
    if (soff < 4096) gload16(gB + kb_, base_ + 8192 + soff);       \
  } while (0)

  f32x4 acc[2][4] = {};
  STAGE(0, 0);
  __syncthreads();
  for (int kt = 0; kt < ND / 32; ++kt) {
    const int cur = kt & 1;
    if (kt + 1 < ND / 32) STAGE(kt + 1, cur ^ 1);   // prefetch overlaps compute
    const unsigned char* bb = &lds[cur * 12288];
    s16x8 av[2], bv[4];
#pragma unroll
    for (int m = 0; m < 2; ++m) av[m] = *(const s16x8*)&bb[aoff[m]];
#pragma unroll
    for (int n = 0; n < 4; ++n) bv[n] = *(const s16x8*)&bb[boff[n]];
#pragma unroll
    for (int m = 0; m < 2; ++m)
#pragma unroll
      for (int n = 0; n < 4; ++n)
        acc[m][n] = __builtin_amdgcn_mfma_f32_16x16x32_bf16(av[m], bv[n], acc[m][n], 0, 0, 0);
    __syncthreads();
  }
#undef STAGE

  // dump v-tile (+bias) to LDS bf16, [128][68]
  unsigned short* vt = (unsigned short*)lds;
#pragma unroll
  for (int m = 0; m < 2; ++m) {
#pragma unroll
    for (int n = 0; n < 4; ++n) {
      const int rb = wv * 32 + m * 16 + fq * 4;
      const int cc = n * 16 + fr;
      const float bbv = bias[n0 + cc];
#pragma unroll
      for (int j = 0; j < 4; ++j)
        vt[(rb + j) * 68 + cc] = f2bf(acc[m][n][j] + bbv);
    }
  }
  __syncthreads();

  // conv tail: thread owns col-quad cq (16 thr x 4 = 64 cols), 7 rows.
  const int cq = (t & 15) * 4;
  const int r0 = 8 + (t >> 4) * 7;
  const int h = n0 >> 6;             // whole block = one head
  float4 win[NK];
#pragma unroll
  for (int k = 0; k < NK; ++k) {
    ushort4 u = *(const ushort4*)&vt[(r0 - 4 + k) * 68 + cq];
    win[k] = make_float4(bf2f(u.x), bf2f(u.y), bf2f(u.z), bf2f(u.w));
  }
#pragma unroll
  for (int i = 0; i < 7; ++i) {
    const int r = r0 + i;
    const long g = mo + r - 8;            // global output row (b*NL + l)
    if (g < (long)NB * NL) {
      const int l = (int)(g & (NL - 1));
      const float* wp = &w[((size_t)g * NH + h) * NK];
      float4 a = make_float4(0.f, 0.f, 0.f, 0.f);
#pragma unroll
      for (int k = 0; k < NK; ++k) {
        const int lk = l + k - NPAD;
        if (lk >= 0 && lk < NL) {
          const float wk = wp[k];
          a.x = fmaf(wk, win[k].x, a.x);
          a.y = fmaf(wk, win[k].y, a.y);
          a.z = fmaf(wk, win[k].z, a.z);
          a.w = fmaf(wk, win[k].w, a.w);
        }
      }
      *(float4*)&out[(size_t)g * ND + n0 + cq] = a;
    }
    if (i < 6) {
#pragma unroll
      for (int k = 0; k < NK - 1; ++k) win[k] = win[k + 1];
      ushort4 u = *(const ushort4*)&vt[(r + 5) * 68 + cq];
      win[NK - 1] = make_float4(bf2f(u.x), bf2f(u.y), bf2f(u.z), bf2f(u.w));
    }
  }
}

// ---------------------------------------------------------------------------
extern "C" void kernel_launch(void* const* d_in, const int* in_sizes, int n_in,
                              void* d_out, int out_size, void* d_ws, size_t ws_size,
                              hipStream_t stream) {
  const float* query = (const float*)d_in[0];
  const float* dw_w  = (const float*)d_in[1];
  const float* pw_w  = (const float*)d_in[2];
  const float* pw_b  = (const float*)d_in[3];
  const float* ak_w  = (const float*)d_in[4];
  const float* ak_b  = (const float*)d_in[5];
  const float* pt_w  = (const float*)d_in[6];
  const float* pt_b  = (const float*)d_in[7];
  float* out = (float*)d_out;

  // workspace: w first (gives qb a safe negative-offset apron), then qb, ptb…
  float* w = (float*)d_ws;                                        // 3.54MB
  unsigned short* qb  = (unsigned short*)(w + (size_t)NB * NL * NH * NK); // 12.6MB
  unsigned short* ptb = qb + (size_t)NB * NL * ND;                // 1.18MB
  unsigned short* pwb = ptb + (size_t)ND * ND;                    // 98KB
  unsigned short* akp = pwb + (size_t)NH * NIPG * NIPG;           // 24.6KB

  prep<<<ND * ND / 4 / 256, 256, 0, stream>>>(pt_w, pw_w, ak_w, ptb, pwb, akp);

  dim3 g2(NL / 64, NH, NB);
  attn_w<<<g2, 256, 0, stream>>>(query, dw_w, pwb, pw_b, akp, ak_b, w, qb);

  dim3 g3((NB * NL + MT - 1) / MT, ND / 64, 1);
  gemm_conv<<<g3, 256, 0, stream>>>(qb, ptb, pt_b, w, out);
}